// Round 1
// baseline (2356.484 us; speedup 1.0000x reference)
//
#include <hip/hip_runtime.h>

#define HID 256
#define VOC 50257
#define NTOK 4096
#define NCT 393                    // ceil(VOC / 128)
#define LN_EPS 1e-3f
#define PROB_ELEMS 205852672      // 4096 * 50257

typedef __attribute__((ext_vector_type(8))) short bf16x8;
typedef __attribute__((ext_vector_type(4))) float f32x4;

__device__ inline unsigned short f2bf(float f) {
    unsigned int u = __builtin_bit_cast(unsigned int, f);
    unsigned int r = u + 0x7FFFu + ((u >> 16) & 1u);
    return (unsigned short)(r >> 16);
}
__device__ inline float bf2f(unsigned short b) {
    unsigned int u = ((unsigned int)b) << 16;
    return __builtin_bit_cast(float, u);
}

// ---------------------------------------------------------------- conv f32->bf16
__global__ void conv_f32_bf16(const float* __restrict__ src,
                              unsigned short* __restrict__ dst, int n4) {
    int i = blockIdx.x * blockDim.x + threadIdx.x;
    int stride = gridDim.x * blockDim.x;
    for (; i < n4; i += stride) {
        float4 v = reinterpret_cast<const float4*>(src)[i];
        ushort4 o;
        o.x = f2bf(v.x); o.y = f2bf(v.y); o.z = f2bf(v.z); o.w = f2bf(v.w);
        reinterpret_cast<ushort4*>(dst)[i] = o;
    }
}

// ---------------------------------------------------------------- expert GEMM
// C[4096, 2560] = xbf[4096,256] @ Wcat[256,2560] + bias  (10 experts of 256 cols)
__global__ __launch_bounds__(256) void expert_gemm(
    const unsigned short* __restrict__ xbf,
    const float* __restrict__ Wsh, const float* __restrict__ bsh,
    const float* __restrict__ Wsp, const float* __restrict__ bsp,
    float* __restrict__ cexp) {
    __shared__ unsigned short sA[64 * 256];
    __shared__ unsigned short sB[128 * 256];
    int bid = blockIdx.x;
    int rt = bid & 63;          // 64 row tiles
    int ct = bid >> 6;          // 20 col tiles
    int row0 = rt * 64, col0 = ct * 128;
    int tid = threadIdx.x;

    // stage A rows (swizzled: 16B chunk index ^ (row & 7))
#pragma unroll
    for (int i = 0; i < 8; ++i) {
        int id = tid + i * 256;
        int r = id >> 5, c = id & 31;
        bf16x8 v = *reinterpret_cast<const bf16x8*>(xbf + (row0 + r) * 256 + c * 8);
        *reinterpret_cast<bf16x8*>(sA + r * 256 + ((c ^ (r & 7)) * 8)) = v;
    }
    // stage B transposed from W[k][h] (f32) -> sB[j][k] bf16
    {
        int j = tid & 127, kh = tid >> 7;
        int gcol = col0 + j;
        int e = gcol >> 8, h = gcol & 255;
        const float* Wp = (e < 2) ? (Wsh + e * 65536) : (Wsp + (e - 2) * 65536);
        for (int k = kh * 128; k < kh * 128 + 128; ++k) {
            unsigned short b = f2bf(Wp[k * 256 + h]);
            int kc = k >> 3, ki = k & 7;
            sB[j * 256 + ((kc ^ (j & 7)) * 8) + ki] = b;
        }
    }
    __syncthreads();

    int lane = tid & 63, wave = tid >> 6;
    int wcol = wave * 32;
    int lrow = lane & 15, g = lane >> 4;
    f32x4 zero4 = {0.f, 0.f, 0.f, 0.f};
    f32x4 acc[4][2];
#pragma unroll
    for (int mf = 0; mf < 4; ++mf)
#pragma unroll
        for (int nf = 0; nf < 2; ++nf) acc[mf][nf] = zero4;

#pragma unroll
    for (int ks = 0; ks < 8; ++ks) {
        int kc = ks * 4 + g;           // 8-elem chunk index of this lane's k
        bf16x8 a[4], b[2];
#pragma unroll
        for (int mf = 0; mf < 4; ++mf) {
            int r = mf * 16 + lrow;
            a[mf] = *reinterpret_cast<const bf16x8*>(sA + r * 256 + ((kc ^ (r & 7)) * 8));
        }
#pragma unroll
        for (int nf = 0; nf < 2; ++nf) {
            int j = wcol + nf * 16 + lrow;
            b[nf] = *reinterpret_cast<const bf16x8*>(sB + j * 256 + ((kc ^ (j & 7)) * 8));
        }
#pragma unroll
        for (int mf = 0; mf < 4; ++mf)
#pragma unroll
            for (int nf = 0; nf < 2; ++nf)
                acc[mf][nf] = __builtin_amdgcn_mfma_f32_16x16x32_bf16(a[mf], b[nf], acc[mf][nf], 0, 0, 0);
    }

#pragma unroll
    for (int nf = 0; nf < 2; ++nf) {
        int col = col0 + wcol + nf * 16 + lrow;
        int e = col >> 8, h = col & 255;
        float bias = (e < 2) ? bsh[e * 256 + h] : bsp[(e - 2) * 256 + h];
#pragma unroll
        for (int mf = 0; mf < 4; ++mf)
#pragma unroll
            for (int r = 0; r < 4; ++r) {
                int row = row0 + mf * 16 + g * 4 + r;
                cexp[row * 2560 + col] = acc[mf][nf][r] + bias;
            }
    }
}

// ---------------------------------------------------------------- gates + combine + LN + residual
__global__ __launch_bounds__(256) void combine_ln(
    const float* __restrict__ x, const int* __restrict__ xb,
    const float* __restrict__ wg, const float* __restrict__ cexp,
    const float* __restrict__ gamma, const float* __restrict__ beta,
    unsigned short* __restrict__ ebf) {
    __shared__ float sx[256];
    __shared__ float sg[4];
    __shared__ float rs[4], rq[4];
    int n = blockIdx.x, h = threadIdx.x;
    float xv = x[n * 256 + h];
    sx[h] = xv;
    __syncthreads();
    int xbn = xb[n];
    float eo;
    if (xbn == 0) {
        // selected output is zeros -> LN(0) = beta
        eo = beta[h] + xv;
    } else {
        int t = xbn - 1;
        int wv = h >> 6, lane = h & 63;
        // gate logits: wave wv computes logit for expert wv
        float p = 0.f;
        const float* wgt = wg + t * 1024;
#pragma unroll
        for (int i = 0; i < 4; ++i) {
            int d = lane * 4 + i;
            p += sx[d] * wgt[d * 4 + wv];
        }
#pragma unroll
        for (int off = 32; off; off >>= 1) p += __shfl_down(p, off);
        if (lane == 0) sg[wv] = p;
        __syncthreads();
        float g0 = sg[0], g1 = sg[1], g2 = sg[2], g3 = sg[3];
        float mx = fmaxf(fmaxf(g0, g1), fmaxf(g2, g3));
        float e0 = __expf(g0 - mx), e1 = __expf(g1 - mx);
        float e2 = __expf(g2 - mx), e3 = __expf(g3 - mx);
        float inv = 1.f / (e0 + e1 + e2 + e3);
        const float* cr = cexp + (size_t)n * 2560;
        float o = (e0 * cr[h] + e1 * cr[256 + h] +
                   e2 * cr[512 + t * 512 + h] + e3 * cr[768 + t * 512 + h]) * inv;
        // LayerNorm across the 256 threads
        float s = o, q = o * o;
#pragma unroll
        for (int off = 32; off; off >>= 1) { s += __shfl_down(s, off); q += __shfl_down(q, off); }
        if (lane == 0) { rs[wv] = s; rq[wv] = q; }
        __syncthreads();
        float mu = (rs[0] + rs[1] + rs[2] + rs[3]) * (1.f / 256.f);
        float ex2 = (rq[0] + rq[1] + rq[2] + rq[3]) * (1.f / 256.f);
        float var = ex2 - mu * mu;
        eo = gamma[h] * (o - mu) * rsqrtf(var + LN_EPS) + beta[h] + xv;
    }
    ebf[n * 256 + h] = f2bf(eo);
}

// ---------------------------------------------------------------- vocab GEMM
// PASS 0: per-(row, coltile) partial max / sumexp.  PASS 1: write prob.
template <int PASS>
__global__ __launch_bounds__(256) void big_gemm(
    const unsigned short* __restrict__ ebf,
    const unsigned short* __restrict__ embbf,
    const float* __restrict__ vbias,
    float* __restrict__ pmax, float* __restrict__ psum,
    const float* __restrict__ lse,
    float* __restrict__ prob) {
    __shared__ unsigned short sA[64 * 256];
    __shared__ unsigned short sB[128 * 256];
    __shared__ float smax[4][64];
    __shared__ float ssum[4][64];
    __shared__ float slse[64];

    int bid = blockIdx.x;
    int rt = bid & 63;            // 64 row tiles
    int ct = bid >> 6;            // 393 col tiles
    int row0 = rt * 64, col0 = ct * 128;
    int tid = threadIdx.x;

    if (PASS == 1 && tid < 64) slse[tid] = lse[row0 + tid];

#pragma unroll
    for (int i = 0; i < 8; ++i) {
        int id = tid + i * 256;
        int r = id >> 5, c = id & 31;
        bf16x8 v = *reinterpret_cast<const bf16x8*>(ebf + (row0 + r) * 256 + c * 8);
        *reinterpret_cast<bf16x8*>(sA + r * 256 + ((c ^ (r & 7)) * 8)) = v;
    }
    bf16x8 zero8 = {0, 0, 0, 0, 0, 0, 0, 0};
#pragma unroll
    for (int i = 0; i < 16; ++i) {
        int id = tid + i * 256;
        int j = id >> 5, c = id & 31;
        int v = col0 + j;
        bf16x8 val = zero8;
        if (v < VOC) val = *reinterpret_cast<const bf16x8*>(embbf + (size_t)v * 256 + c * 8);
        *reinterpret_cast<bf16x8*>(sB + j * 256 + ((c ^ (j & 7)) * 8)) = val;
    }
    __syncthreads();

    int lane = tid & 63, wave = tid >> 6;
    int wcol = wave * 32;
    int lrow = lane & 15, g = lane >> 4;
    f32x4 zero4 = {0.f, 0.f, 0.f, 0.f};
    f32x4 acc[4][2];
#pragma unroll
    for (int mf = 0; mf < 4; ++mf)
#pragma unroll
        for (int nf = 0; nf < 2; ++nf) acc[mf][nf] = zero4;

#pragma unroll
    for (int ks = 0; ks < 8; ++ks) {
        int kc = ks * 4 + g;
        bf16x8 a[4], b[2];
#pragma unroll
        for (int mf = 0; mf < 4; ++mf) {
            int r = mf * 16 + lrow;
            a[mf] = *reinterpret_cast<const bf16x8*>(sA + r * 256 + ((kc ^ (r & 7)) * 8));
        }
#pragma unroll
        for (int nf = 0; nf < 2; ++nf) {
            int j = wcol + nf * 16 + lrow;
            b[nf] = *reinterpret_cast<const bf16x8*>(sB + j * 256 + ((kc ^ (j & 7)) * 8));
        }
#pragma unroll
        for (int mf = 0; mf < 4; ++mf)
#pragma unroll
            for (int nf = 0; nf < 2; ++nf)
                acc[mf][nf] = __builtin_amdgcn_mfma_f32_16x16x32_bf16(a[mf], b[nf], acc[mf][nf], 0, 0, 0);
    }

    int colg[2]; float bs[2]; bool vd[2];
#pragma unroll
    for (int nf = 0; nf < 2; ++nf) {
        colg[nf] = col0 + wcol + nf * 16 + lrow;
        vd[nf] = colg[nf] < VOC;
        bs[nf] = vd[nf] ? vbias[colg[nf]] : 0.f;
    }

    if (PASS == 0) {
#pragma unroll
        for (int mf = 0; mf < 4; ++mf) {
#pragma unroll
            for (int r = 0; r < 4; ++r) {
                float v0 = vd[0] ? acc[mf][0][r] + bs[0] : -__builtin_inff();
                float v1 = vd[1] ? acc[mf][1][r] + bs[1] : -__builtin_inff();
                float m = fmaxf(v0, v1);
#pragma unroll
                for (int off = 1; off < 16; off <<= 1) m = fmaxf(m, __shfl_xor(m, off));
                float s = (vd[0] ? __expf(v0 - m) : 0.f) + (vd[1] ? __expf(v1 - m) : 0.f);
#pragma unroll
                for (int off = 1; off < 16; off <<= 1) s += __shfl_xor(s, off);
                if (lrow == 0) {
                    int row = mf * 16 + g * 4 + r;
                    smax[wave][row] = m;
                    ssum[wave][row] = s;
                }
            }
        }
        __syncthreads();
        if (tid < 64) {
            float m = smax[0][tid];
#pragma unroll
            for (int w = 1; w < 4; ++w) m = fmaxf(m, smax[w][tid]);
            float s = 0.f;
#pragma unroll
            for (int w = 0; w < 4; ++w) {
                float ps = ssum[w][tid];
                if (ps > 0.f) s += ps * __expf(smax[w][tid] - m);
            }
            pmax[(size_t)(row0 + tid) * NCT + ct] = m;
            psum[(size_t)(row0 + tid) * NCT + ct] = s;
        }
    } else {
#pragma unroll
        for (int mf = 0; mf < 4; ++mf)
#pragma unroll
            for (int nf = 0; nf < 2; ++nf) {
                if (!vd[nf]) continue;
#pragma unroll
                for (int r = 0; r < 4; ++r) {
                    int row = mf * 16 + g * 4 + r;
                    float lg = acc[mf][nf][r] + bs[nf];
                    prob[(size_t)(row0 + row) * VOC + colg[nf]] = __expf(lg - slse[row]);
                }
            }
    }
}

// ---------------------------------------------------------------- finalize: lse + loss
__global__ __launch_bounds__(64) void finalize_k(
    const float* __restrict__ pmax, const float* __restrict__ psum,
    const unsigned short* __restrict__ ebf, const unsigned short* __restrict__ embbf,
    const float* __restrict__ vbias, const int* __restrict__ labels,
    float* __restrict__ lse, float* __restrict__ loss) {
    int n = blockIdx.x, lane = threadIdx.x;
    float m = -__builtin_inff(), s = 0.f;
    for (int ct = lane; ct < NCT; ct += 64) {
        float pm = pmax[(size_t)n * NCT + ct];
        float ps = psum[(size_t)n * NCT + ct];
        if (ps > 0.f) {
            if (pm > m) { s = s * __expf(m - pm) + ps; m = pm; }
            else         s += ps * __expf(pm - m);
        }
    }
#pragma unroll
    for (int off = 1; off < 64; off <<= 1) {
        float om = __shfl_xor(m, off), os = __shfl_xor(s, off);
        if (om > m)      { s = s * __expf(m - om) + os; m = om; }
        else if (os > 0.f) s += os * __expf(om - m);
    }
    float lsev = m + logf(s);
    // label logit (bf16 dot, consistent with GEMM inputs)
    int lf = labels[n];
    const unsigned short* ev = ebf + n * 256;
    const unsigned short* mv = embbf + (size_t)lf * 256;
    float p = 0.f;
#pragma unroll
    for (int i = 0; i < 4; ++i) p += bf2f(ev[lane * 4 + i]) * bf2f(mv[lane * 4 + i]);
#pragma unroll
    for (int off = 1; off < 64; off <<= 1) p += __shfl_xor(p, off);
    if (lane == 0) {
        lse[n] = lsev;
        loss[n] = lsev - (p + vbias[lf]);
    }
}

// ---------------------------------------------------------------- launch
extern "C" void kernel_launch(void* const* d_in, const int* in_sizes, int n_in,
                              void* d_out, int out_size, void* d_ws, size_t ws_size,
                              hipStream_t stream) {
    const float* x      = (const float*)d_in[0];
    const int*   labels = (const int*)d_in[1];
    const int*   xb     = (const int*)d_in[2];
    const float* Wsh    = (const float*)d_in[3];
    const float* bsh    = (const float*)d_in[4];
    const float* Wsp    = (const float*)d_in[5];
    const float* bsp    = (const float*)d_in[6];
    const float* wg     = (const float*)d_in[7];
    const float* vbias  = (const float*)d_in[8];
    const float* emb    = (const float*)d_in[9];
    const float* gamma  = (const float*)d_in[10];
    const float* beta   = (const float*)d_in[11];

    char* ws = (char*)d_ws;
    unsigned short* xbf   = (unsigned short*)(ws + 0);          //  2 MB
    unsigned short* embbf = (unsigned short*)(ws + 2097152);    // 25.7 MB
    float* cexp           = (float*)(ws + 27828736);            // 41.9 MB
    unsigned short* ebf   = (unsigned short*)(ws + 69771776);   //  2 MB
    float* pmax           = (float*)(ws + 71868928);            //  6.4 MB
    float* psum           = (float*)(ws + 78307840);            //  6.4 MB
    float* lse            = (float*)(ws + 84746752);            // 16 KB

    float* prob = (float*)d_out;
    float* loss = prob + PROB_ELEMS;

    conv_f32_bf16<<<dim3(512), dim3(256), 0, stream>>>(x, xbf, NTOK * HID / 4);
    conv_f32_bf16<<<dim3(2048), dim3(256), 0, stream>>>(emb, embbf, VOC * HID / 4);
    expert_gemm<<<dim3(64 * 20), dim3(256), 0, stream>>>(xbf, Wsh, bsh, Wsp, bsp, cexp);
    combine_ln<<<dim3(NTOK), dim3(256), 0, stream>>>(x, xb, wg, cexp, gamma, beta, ebf);
    big_gemm<0><<<dim3(64 * NCT), dim3(256), 0, stream>>>(ebf, embbf, vbias, pmax, psum, nullptr, nullptr);
    finalize_k<<<dim3(NTOK), dim3(64), 0, stream>>>(pmax, psum, ebf, embbf, vbias, labels, lse, loss);
    big_gemm<1><<<dim3(64 * NCT), dim3(256), 0, stream>>>(ebf, embbf, vbias, nullptr, nullptr, lse, prob);
}

// Round 2
// 784.619 us; speedup vs baseline: 3.0033x; 3.0033x over previous
//
#include <hip/hip_runtime.h>

#define HID 256
#define VOC 50257
#define NTOK 4096
#define NCT2 786                  // ceil(VOC / 64)
#define CG 8                      // column groups (== XCDs)
#define LN_EPS 1e-3f
#define PROB_ELEMS 205852672      // 4096 * 50257

typedef __attribute__((ext_vector_type(8))) short bf16x8;
typedef __attribute__((ext_vector_type(4))) float f32x4;

__device__ inline unsigned short f2bf(float f) {
    unsigned int u = __builtin_bit_cast(unsigned int, f);
    unsigned int r = u + 0x7FFFu + ((u >> 16) & 1u);
    return (unsigned short)(r >> 16);
}
__device__ inline float bf2f(unsigned short b) {
    unsigned int u = ((unsigned int)b) << 16;
    return __builtin_bit_cast(float, u);
}

// ---------------------------------------------------------------- conv f32->bf16
__global__ void conv_f32_bf16(const float* __restrict__ src,
                              unsigned short* __restrict__ dst, int n4) {
    int i = blockIdx.x * blockDim.x + threadIdx.x;
    int stride = gridDim.x * blockDim.x;
    for (; i < n4; i += stride) {
        float4 v = reinterpret_cast<const float4*>(src)[i];
        ushort4 o;
        o.x = f2bf(v.x); o.y = f2bf(v.y); o.z = f2bf(v.z); o.w = f2bf(v.w);
        reinterpret_cast<ushort4*>(dst)[i] = o;
    }
}

// ---------------------------------------------------------------- W transpose: W[e][k][h] f32 -> Wt[e*256+h][k] bf16
__global__ __launch_bounds__(256) void wt_transpose(
    const float* __restrict__ Wsh, const float* __restrict__ Wsp,
    unsigned short* __restrict__ Wtbf) {
    __shared__ float t[64][65];
    int gcol0 = blockIdx.x * 64;       // 0..2560 step 64 (never crosses expert)
    int k0 = blockIdx.y * 64;
    int e = gcol0 >> 8, h0 = gcol0 & 255;
    const float* Wp = (e < 2) ? (Wsh + e * 65536) : (Wsp + (e - 2) * 65536);
    int tid = threadIdx.x;
#pragma unroll
    for (int i = 0; i < 16; ++i) {
        int id = tid + i * 256;
        int k = id >> 6, h = id & 63;
        t[k][h] = Wp[(k0 + k) * 256 + h0 + h];
    }
    __syncthreads();
#pragma unroll
    for (int i = 0; i < 4; ++i) {
        int id = tid + i * 256;        // 0..1023
        int h = id >> 4, kq = id & 15;
        ushort4 o;
        o.x = f2bf(t[kq * 4 + 0][h]); o.y = f2bf(t[kq * 4 + 1][h]);
        o.z = f2bf(t[kq * 4 + 2][h]); o.w = f2bf(t[kq * 4 + 3][h]);
        *reinterpret_cast<ushort4*>(Wtbf + (size_t)(gcol0 + h) * 256 + k0 + kq * 4) = o;
    }
}

// ---------------------------------------------------------------- expert GEMM
// C[4096, 2560] = xbf[4096,256] @ Wt^T + bias  (10 experts of 256 cols)
__global__ __launch_bounds__(256) void expert_gemm(
    const unsigned short* __restrict__ xbf,
    const unsigned short* __restrict__ Wtbf,
    const float* __restrict__ bsh, const float* __restrict__ bsp,
    float* __restrict__ cexp) {
    __shared__ unsigned short sA[64 * 256];
    __shared__ unsigned short sB[128 * 256];
    int bid = blockIdx.x;
    int rt = bid & 63;          // 64 row tiles
    int ct = bid >> 6;          // 20 col tiles
    int row0 = rt * 64, col0 = ct * 128;
    int tid = threadIdx.x;

#pragma unroll
    for (int i = 0; i < 8; ++i) {
        int id = tid + i * 256;
        int r = id >> 5, c = id & 31;
        bf16x8 v = *reinterpret_cast<const bf16x8*>(xbf + (row0 + r) * 256 + c * 8);
        *reinterpret_cast<bf16x8*>(sA + r * 256 + ((c ^ (r & 7)) * 8)) = v;
    }
#pragma unroll
    for (int i = 0; i < 16; ++i) {
        int id = tid + i * 256;
        int j = id >> 5, c = id & 31;
        bf16x8 v = *reinterpret_cast<const bf16x8*>(Wtbf + (size_t)(col0 + j) * 256 + c * 8);
        *reinterpret_cast<bf16x8*>(sB + j * 256 + ((c ^ (j & 7)) * 8)) = v;
    }
    __syncthreads();

    int lane = tid & 63, wave = tid >> 6;
    int wcol = wave * 32;
    int lrow = lane & 15, g = lane >> 4;
    f32x4 zero4 = {0.f, 0.f, 0.f, 0.f};
    f32x4 acc[4][2];
#pragma unroll
    for (int mf = 0; mf < 4; ++mf)
#pragma unroll
        for (int nf = 0; nf < 2; ++nf) acc[mf][nf] = zero4;

#pragma unroll
    for (int ks = 0; ks < 8; ++ks) {
        int kc = ks * 4 + g;
        bf16x8 a[4], b[2];
#pragma unroll
        for (int mf = 0; mf < 4; ++mf) {
            int r = mf * 16 + lrow;
            a[mf] = *reinterpret_cast<const bf16x8*>(sA + r * 256 + ((kc ^ (r & 7)) * 8));
        }
#pragma unroll
        for (int nf = 0; nf < 2; ++nf) {
            int j = wcol + nf * 16 + lrow;
            b[nf] = *reinterpret_cast<const bf16x8*>(sB + j * 256 + ((kc ^ (j & 7)) * 8));
        }
#pragma unroll
        for (int mf = 0; mf < 4; ++mf)
#pragma unroll
            for (int nf = 0; nf < 2; ++nf)
                acc[mf][nf] = __builtin_amdgcn_mfma_f32_16x16x32_bf16(a[mf], b[nf], acc[mf][nf], 0, 0, 0);
    }

#pragma unroll
    for (int nf = 0; nf < 2; ++nf) {
        int col = col0 + wcol + nf * 16 + lrow;
        int e = col >> 8, h = col & 255;
        float bias = (e < 2) ? bsh[e * 256 + h] : bsp[(e - 2) * 256 + h];
#pragma unroll
        for (int mf = 0; mf < 4; ++mf)
#pragma unroll
            for (int r = 0; r < 4; ++r) {
                int row = row0 + mf * 16 + g * 4 + r;
                cexp[(size_t)row * 2560 + col] = acc[mf][nf][r] + bias;
            }
    }
}

// ---------------------------------------------------------------- gates + combine + LN + residual
__global__ __launch_bounds__(256) void combine_ln(
    const float* __restrict__ x, const int* __restrict__ xb,
    const float* __restrict__ wg, const float* __restrict__ cexp,
    const float* __restrict__ gamma, const float* __restrict__ beta,
    unsigned short* __restrict__ ebf) {
    __shared__ float sx[256];
    __shared__ float sg[4];
    __shared__ float rs[4], rq[4];
    int n = blockIdx.x, h = threadIdx.x;
    float xv = x[n * 256 + h];
    sx[h] = xv;
    __syncthreads();
    int xbn = xb[n];
    float eo;
    if (xbn == 0) {
        eo = beta[h] + xv;
    } else {
        int t = xbn - 1;
        int wv = h >> 6, lane = h & 63;
        float p = 0.f;
        const float* wgt = wg + t * 1024;
#pragma unroll
        for (int i = 0; i < 4; ++i) {
            int d = lane * 4 + i;
            p += sx[d] * wgt[d * 4 + wv];
        }
#pragma unroll
        for (int off = 32; off; off >>= 1) p += __shfl_down(p, off);
        if (lane == 0) sg[wv] = p;
        __syncthreads();
        float g0 = sg[0], g1 = sg[1], g2 = sg[2], g3 = sg[3];
        float mx = fmaxf(fmaxf(g0, g1), fmaxf(g2, g3));
        float e0 = __expf(g0 - mx), e1 = __expf(g1 - mx);
        float e2 = __expf(g2 - mx), e3 = __expf(g3 - mx);
        float inv = 1.f / (e0 + e1 + e2 + e3);
        const float* cr = cexp + (size_t)n * 2560;
        float o = (e0 * cr[h] + e1 * cr[256 + h] +
                   e2 * cr[512 + t * 512 + h] + e3 * cr[768 + t * 512 + h]) * inv;
        float s = o, q = o * o;
#pragma unroll
        for (int off = 32; off; off >>= 1) { s += __shfl_down(s, off); q += __shfl_down(q, off); }
        if (lane == 0) { rs[wv] = s; rq[wv] = q; }
        __syncthreads();
        float mu = (rs[0] + rs[1] + rs[2] + rs[3]) * (1.f / 256.f);
        float ex2 = (rq[0] + rq[1] + rq[2] + rq[3]) * (1.f / 256.f);
        float var = ex2 - mu * mu;
        eo = gamma[h] * (o - mu) * rsqrtf(var + LN_EPS) + beta[h] + xv;
    }
    ebf[n * 256 + h] = f2bf(eo);
}

// ---------------------------------------------------------------- vocab GEMM (persistent, 2-phase dbuf)
// grid: 32 row-tiles x 8 col-groups = 256 blocks, 512 threads (8 waves, 4x2)
// PASS 0: psum[row][ct] = sum_cols exp(logit).  PASS 1: prob = exp(logit)/denom[row].
template <int PASS>
__global__ __launch_bounds__(512) void big_gemm(
    const unsigned short* __restrict__ ebf,
    const unsigned short* __restrict__ embbf,
    const float* __restrict__ vbias,
    float* __restrict__ psum,
    const float* __restrict__ denom,
    float* __restrict__ prob) {
    __shared__ unsigned short sA[128 * 256];      // 64 KB, swizzled
    __shared__ unsigned short sB[2][64 * 256];    // 2 x 32 KB, swizzled
    __shared__ float sRed[2][128];

    int bid = blockIdx.x;
    int rt = bid >> 3;           // 32 row tiles
    int cg = bid & 7;            // col group == XCD
    int row0 = rt * 128;
    int tid = threadIdx.x;
    int wave = tid >> 6, lane = tid & 63;
    int lrow = lane & 15, g = lane >> 4;
    int wr = wave >> 1, wc = wave & 1;
    int nmy = (NCT2 - cg + CG - 1) / CG;

    // ---- stage A once: wave w stages local rows [w*16, w*16+16)
#pragma unroll
    for (int i = 0; i < 8; ++i) {
        int jb = wave * 16 + i * 2;
        int j = jb + (lane >> 5);
        int cslot = lane & 31;
        const unsigned short* src =
            ebf + (size_t)(row0 + j) * 256 + ((cslot ^ (j & 7)) * 8);
        __builtin_amdgcn_global_load_lds(
            (const __attribute__((address_space(1))) void*)src,
            (__attribute__((address_space(3))) void*)(sA + jb * 256), 16, 0, 0);
    }
    // ---- stage B tile 0
    {
        int col0 = cg * 64;
#pragma unroll
        for (int i = 0; i < 4; ++i) {
            int jb = wave * 8 + i * 2;
            int j = jb + (lane >> 5);
            int cslot = lane & 31;
            int col = col0 + j; if (col > VOC - 1) col = VOC - 1;
            const unsigned short* src =
                embbf + (size_t)col * 256 + ((cslot ^ (j & 7)) * 8);
            __builtin_amdgcn_global_load_lds(
                (const __attribute__((address_space(1))) void*)src,
                (__attribute__((address_space(3))) void*)(sB[0] + jb * 256), 16, 0, 0);
        }
    }
    asm volatile("s_waitcnt vmcnt(0)" ::: "memory");
    __syncthreads();

    float invd[2][4];
    if (PASS == 1) {
#pragma unroll
        for (int mf = 0; mf < 2; ++mf)
#pragma unroll
            for (int r = 0; r < 4; ++r)
                invd[mf][r] = 1.f / denom[row0 + wr * 32 + mf * 16 + g * 4 + r];
    }

    for (int it = 0; it < nmy; ++it) {
        int ct = cg + it * CG;
        // issue next B tile
        if (it + 1 < nmy) {
            int col0n = (ct + CG) * 64;
            unsigned short* dstb = sB[(it + 1) & 1];
#pragma unroll
            for (int i = 0; i < 4; ++i) {
                int jb = wave * 8 + i * 2;
                int j = jb + (lane >> 5);
                int cslot = lane & 31;
                int col = col0n + j; if (col > VOC - 1) col = VOC - 1;
                const unsigned short* src =
                    embbf + (size_t)col * 256 + ((cslot ^ (j & 7)) * 8);
                __builtin_amdgcn_global_load_lds(
                    (const __attribute__((address_space(1))) void*)src,
                    (__attribute__((address_space(3))) void*)(dstb + jb * 256), 16, 0, 0);
            }
        }
        // bias for my 2 columns
        int col0 = ct * 64;
        int colg[2]; float bs[2]; bool vd[2];
#pragma unroll
        for (int nf = 0; nf < 2; ++nf) {
            colg[nf] = col0 + wc * 32 + nf * 16 + lrow;
            vd[nf] = colg[nf] < VOC;
            bs[nf] = vd[nf] ? vbias[colg[nf]] : -1e4f;
        }

        const unsigned short* sBc = sB[it & 1];
        f32x4 zero4 = {0.f, 0.f, 0.f, 0.f};
        f32x4 acc[2][2];
#pragma unroll
        for (int mf = 0; mf < 2; ++mf)
#pragma unroll
            for (int nf = 0; nf < 2; ++nf) acc[mf][nf] = zero4;

#pragma unroll
        for (int ks = 0; ks < 8; ++ks) {
            int kc = ks * 4 + g;
            int sw = (kc ^ (lrow & 7)) * 8;
            bf16x8 a[2], b[2];
#pragma unroll
            for (int mf = 0; mf < 2; ++mf)
                a[mf] = *reinterpret_cast<const bf16x8*>(
                    sA + (wr * 32 + mf * 16 + lrow) * 256 + sw);
#pragma unroll
            for (int nf = 0; nf < 2; ++nf)
                b[nf] = *reinterpret_cast<const bf16x8*>(
                    sBc + (wc * 32 + nf * 16 + lrow) * 256 + sw);
#pragma unroll
            for (int mf = 0; mf < 2; ++mf)
#pragma unroll
                for (int nf = 0; nf < 2; ++nf)
                    acc[mf][nf] = __builtin_amdgcn_mfma_f32_16x16x32_bf16(
                        a[mf], b[nf], acc[mf][nf], 0, 0, 0);
        }

        if (PASS == 0) {
#pragma unroll
            for (int mf = 0; mf < 2; ++mf)
#pragma unroll
                for (int r = 0; r < 4; ++r) {
                    float v = __expf(acc[mf][0][r] + bs[0]) + __expf(acc[mf][1][r] + bs[1]);
#pragma unroll
                    for (int off = 1; off < 16; off <<= 1) v += __shfl_xor(v, off);
                    if (lrow == 0)
                        sRed[wc][wr * 32 + mf * 16 + g * 4 + r] = v;
                }
            __syncthreads();
            if (tid < 128)
                psum[(size_t)(row0 + tid) * NCT2 + ct] = sRed[0][tid] + sRed[1][tid];
            __syncthreads();
        } else {
#pragma unroll
            for (int mf = 0; mf < 2; ++mf)
#pragma unroll
                for (int nf = 0; nf < 2; ++nf) {
                    if (!vd[nf]) continue;
#pragma unroll
                    for (int r = 0; r < 4; ++r) {
                        int row = row0 + wr * 32 + mf * 16 + g * 4 + r;
                        prob[(size_t)row * VOC + colg[nf]] =
                            __expf(acc[mf][nf][r] + bs[nf]) * invd[mf][r];
                    }
                }
            __syncthreads();
        }
    }
}

// ---------------------------------------------------------------- finalize: denom + loss
__global__ __launch_bounds__(64) void finalize_k(
    const float* __restrict__ psum,
    const unsigned short* __restrict__ ebf, const unsigned short* __restrict__ embbf,
    const float* __restrict__ vbias, const int* __restrict__ labels,
    float* __restrict__ denom, float* __restrict__ loss) {
    int n = blockIdx.x, lane = threadIdx.x;
    float s = 0.f;
    for (int ct = lane; ct < NCT2; ct += 64) s += psum[(size_t)n * NCT2 + ct];
#pragma unroll
    for (int off = 1; off < 64; off <<= 1) s += __shfl_xor(s, off);
    int lf = labels[n];
    const unsigned short* ev = ebf + n * 256;
    const unsigned short* mv = embbf + (size_t)lf * 256;
    float p = 0.f;
#pragma unroll
    for (int i = 0; i < 4; ++i) p += bf2f(ev[lane * 4 + i]) * bf2f(mv[lane * 4 + i]);
#pragma unroll
    for (int off = 1; off < 64; off <<= 1) p += __shfl_xor(p, off);
    if (lane == 0) {
        denom[n] = s;
        loss[n] = logf(s) - (p + vbias[lf]);
    }
}

// ---------------------------------------------------------------- launch
extern "C" void kernel_launch(void* const* d_in, const int* in_sizes, int n_in,
                              void* d_out, int out_size, void* d_ws, size_t ws_size,
                              hipStream_t stream) {
    const float* x      = (const float*)d_in[0];
    const int*   labels = (const int*)d_in[1];
    const int*   xb     = (const int*)d_in[2];
    const float* Wsh    = (const float*)d_in[3];
    const float* bsh    = (const float*)d_in[4];
    const float* Wsp    = (const float*)d_in[5];
    const float* bsp    = (const float*)d_in[6];
    const float* wg     = (const float*)d_in[7];
    const float* vbias  = (const float*)d_in[8];
    const float* emb    = (const float*)d_in[9];
    const float* gamma  = (const float*)d_in[10];
    const float* beta   = (const float*)d_in[11];

    char* ws = (char*)d_ws;
    unsigned short* xbf   = (unsigned short*)(ws + 0);          // 2,097,152
    unsigned short* embbf = (unsigned short*)(ws + 2097152);    // 25,731,584
    float* psum           = (float*)(ws + 27828736);            // 12,877,824 (aliases Wtbf)
    unsigned short* Wtbf  = (unsigned short*)(ws + 27828736);   // 1,310,720 (dead before psum written)
    float* cexp           = (float*)(ws + 40706560);            // 41,943,040
    unsigned short* ebf   = (unsigned short*)(ws + 82649600);   // 2,097,152
    float* denom          = (float*)(ws + 84746752);            // 16,384

    float* prob = (float*)d_out;
    float* loss = prob + PROB_ELEMS;

    conv_f32_bf16<<<dim3(512), dim3(256), 0, stream>>>(x, xbf, NTOK * HID / 4);
    conv_f32_bf16<<<dim3(2048), dim3(256), 0, stream>>>(emb, embbf, VOC * HID / 4);
    wt_transpose<<<dim3(40, 4), dim3(256), 0, stream>>>(Wsh, Wsp, Wtbf);
    expert_gemm<<<dim3(64 * 20), dim3(256), 0, stream>>>(xbf, Wtbf, bsh, bsp, cexp);
    combine_ln<<<dim3(NTOK), dim3(256), 0, stream>>>(x, xb, wg, cexp, gamma, beta, ebf);
    big_gemm<0><<<dim3(256), dim3(512), 0, stream>>>(ebf, embbf, vbias, psum, nullptr, nullptr);
    finalize_k<<<dim3(NTOK), dim3(64), 0, stream>>>(psum, ebf, embbf, vbias, labels, denom, loss);
    big_gemm<1><<<dim3(256), dim3(512), 0, stream>>>(ebf, embbf, vbias, nullptr, denom, prob);
}

// Round 3
// 542.947 us; speedup vs baseline: 4.3402x; 1.4451x over previous
//
#include <hip/hip_runtime.h>

#define HID 256
#define VOC 50257
#define NTOK 4096
#define NCT3 393                  // ceil(VOC / 128)
#define CG 8                      // column groups (== XCDs)
#define TN 128                    // cols per iteration
#define LN_EPS 1e-3f
#define PROB_ELEMS 205852672      // 4096 * 50257

typedef __attribute__((ext_vector_type(8))) short bf16x8;
typedef __attribute__((ext_vector_type(4))) float f32x4;
typedef __attribute__((ext_vector_type(16))) float f32x16;

__device__ inline unsigned short f2bf(float f) {
    unsigned int u = __builtin_bit_cast(unsigned int, f);
    unsigned int r = u + 0x7FFFu + ((u >> 16) & 1u);
    return (unsigned short)(r >> 16);
}
__device__ inline float bf2f(unsigned short b) {
    unsigned int u = ((unsigned int)b) << 16;
    return __builtin_bit_cast(float, u);
}

// ---------------------------------------------------------------- conv f32->bf16
__global__ void conv_f32_bf16(const float* __restrict__ src,
                              unsigned short* __restrict__ dst, int n4) {
    int i = blockIdx.x * blockDim.x + threadIdx.x;
    int stride = gridDim.x * blockDim.x;
    for (; i < n4; i += stride) {
        float4 v = reinterpret_cast<const float4*>(src)[i];
        ushort4 o;
        o.x = f2bf(v.x); o.y = f2bf(v.y); o.z = f2bf(v.z); o.w = f2bf(v.w);
        reinterpret_cast<ushort4*>(dst)[i] = o;
    }
}

// ---------------------------------------------------------------- W transpose: W[e][k][h] f32 -> Wt[e*256+h][k] bf16
__global__ __launch_bounds__(256) void wt_transpose(
    const float* __restrict__ Wsh, const float* __restrict__ Wsp,
    unsigned short* __restrict__ Wtbf) {
    __shared__ float t[64][65];
    int gcol0 = blockIdx.x * 64;
    int k0 = blockIdx.y * 64;
    int e = gcol0 >> 8, h0 = gcol0 & 255;
    const float* Wp = (e < 2) ? (Wsh + e * 65536) : (Wsp + (e - 2) * 65536);
    int tid = threadIdx.x;
#pragma unroll
    for (int i = 0; i < 16; ++i) {
        int id = tid + i * 256;
        int k = id >> 6, h = id & 63;
        t[k][h] = Wp[(k0 + k) * 256 + h0 + h];
    }
    __syncthreads();
#pragma unroll
    for (int i = 0; i < 4; ++i) {
        int id = tid + i * 256;
        int h = id >> 4, kq = id & 15;
        ushort4 o;
        o.x = f2bf(t[kq * 4 + 0][h]); o.y = f2bf(t[kq * 4 + 1][h]);
        o.z = f2bf(t[kq * 4 + 2][h]); o.w = f2bf(t[kq * 4 + 3][h]);
        *reinterpret_cast<ushort4*>(Wtbf + (size_t)(gcol0 + h) * 256 + k0 + kq * 4) = o;
    }
}

// ---------------------------------------------------------------- expert GEMM
__global__ __launch_bounds__(256) void expert_gemm(
    const unsigned short* __restrict__ xbf,
    const unsigned short* __restrict__ Wtbf,
    const float* __restrict__ bsh, const float* __restrict__ bsp,
    float* __restrict__ cexp) {
    __shared__ unsigned short sA[64 * 256];
    __shared__ unsigned short sB[128 * 256];
    int bid = blockIdx.x;
    int rt = bid & 63;
    int ct = bid >> 6;
    int row0 = rt * 64, col0 = ct * 128;
    int tid = threadIdx.x;

#pragma unroll
    for (int i = 0; i < 8; ++i) {
        int id = tid + i * 256;
        int r = id >> 5, c = id & 31;
        bf16x8 v = *reinterpret_cast<const bf16x8*>(xbf + (row0 + r) * 256 + c * 8);
        *reinterpret_cast<bf16x8*>(sA + r * 256 + ((c ^ (r & 7)) * 8)) = v;
    }
#pragma unroll
    for (int i = 0; i < 16; ++i) {
        int id = tid + i * 256;
        int j = id >> 5, c = id & 31;
        bf16x8 v = *reinterpret_cast<const bf16x8*>(Wtbf + (size_t)(col0 + j) * 256 + c * 8);
        *reinterpret_cast<bf16x8*>(sB + j * 256 + ((c ^ (j & 7)) * 8)) = v;
    }
    __syncthreads();

    int lane = tid & 63, wave = tid >> 6;
    int wcol = wave * 32;
    int lrow = lane & 15, g = lane >> 4;
    f32x4 zero4 = {0.f, 0.f, 0.f, 0.f};
    f32x4 acc[4][2];
#pragma unroll
    for (int mf = 0; mf < 4; ++mf)
#pragma unroll
        for (int nf = 0; nf < 2; ++nf) acc[mf][nf] = zero4;

#pragma unroll
    for (int ks = 0; ks < 8; ++ks) {
        int kc = ks * 4 + g;
        bf16x8 a[4], b[2];
#pragma unroll
        for (int mf = 0; mf < 4; ++mf) {
            int r = mf * 16 + lrow;
            a[mf] = *reinterpret_cast<const bf16x8*>(sA + r * 256 + ((kc ^ (r & 7)) * 8));
        }
#pragma unroll
        for (int nf = 0; nf < 2; ++nf) {
            int j = wcol + nf * 16 + lrow;
            b[nf] = *reinterpret_cast<const bf16x8*>(sB + j * 256 + ((kc ^ (j & 7)) * 8));
        }
#pragma unroll
        for (int mf = 0; mf < 4; ++mf)
#pragma unroll
            for (int nf = 0; nf < 2; ++nf)
                acc[mf][nf] = __builtin_amdgcn_mfma_f32_16x16x32_bf16(a[mf], b[nf], acc[mf][nf], 0, 0, 0);
    }

#pragma unroll
    for (int nf = 0; nf < 2; ++nf) {
        int col = col0 + wcol + nf * 16 + lrow;
        int e = col >> 8, h = col & 255;
        float bias = (e < 2) ? bsh[e * 256 + h] : bsp[(e - 2) * 256 + h];
#pragma unroll
        for (int mf = 0; mf < 4; ++mf)
#pragma unroll
            for (int r = 0; r < 4; ++r) {
                int row = row0 + mf * 16 + g * 4 + r;
                cexp[(size_t)row * 2560 + col] = acc[mf][nf][r] + bias;
            }
    }
}

// ---------------------------------------------------------------- gates + combine + LN + residual
__global__ __launch_bounds__(256) void combine_ln(
    const float* __restrict__ x, const int* __restrict__ xb,
    const float* __restrict__ wg, const float* __restrict__ cexp,
    const float* __restrict__ gamma, const float* __restrict__ beta,
    unsigned short* __restrict__ ebf) {
    __shared__ float sx[256];
    __shared__ float sg[4];
    __shared__ float rs[4], rq[4];
    int n = blockIdx.x, h = threadIdx.x;
    float xv = x[n * 256 + h];
    sx[h] = xv;
    __syncthreads();
    int xbn = xb[n];
    float eo;
    if (xbn == 0) {
        eo = beta[h] + xv;
    } else {
        int t = xbn - 1;
        int wv = h >> 6, lane = h & 63;
        float p = 0.f;
        const float* wgt = wg + t * 1024;
#pragma unroll
        for (int i = 0; i < 4; ++i) {
            int d = lane * 4 + i;
            p += sx[d] * wgt[d * 4 + wv];
        }
#pragma unroll
        for (int off = 32; off; off >>= 1) p += __shfl_down(p, off);
        if (lane == 0) sg[wv] = p;
        __syncthreads();
        float g0 = sg[0], g1 = sg[1], g2 = sg[2], g3 = sg[3];
        float mx = fmaxf(fmaxf(g0, g1), fmaxf(g2, g3));
        float e0 = __expf(g0 - mx), e1 = __expf(g1 - mx);
        float e2 = __expf(g2 - mx), e3 = __expf(g3 - mx);
        float inv = 1.f / (e0 + e1 + e2 + e3);
        const float* cr = cexp + (size_t)n * 2560;
        float o = (e0 * cr[h] + e1 * cr[256 + h] +
                   e2 * cr[512 + t * 512 + h] + e3 * cr[768 + t * 512 + h]) * inv;
        float s = o, q = o * o;
#pragma unroll
        for (int off = 32; off; off >>= 1) { s += __shfl_down(s, off); q += __shfl_down(q, off); }
        if (lane == 0) { rs[wv] = s; rq[wv] = q; }
        __syncthreads();
        float mu = (rs[0] + rs[1] + rs[2] + rs[3]) * (1.f / 256.f);
        float ex2 = (rq[0] + rq[1] + rq[2] + rq[3]) * (1.f / 256.f);
        float var = ex2 - mu * mu;
        eo = gamma[h] * (o - mu) * rsqrtf(var + LN_EPS) + beta[h] + xv;
    }
    ebf[n * 256 + h] = f2bf(eo);
}

// ---------------------------------------------------------------- vocab GEMM v3
// Persistent: 32 row-tiles x 8 col-groups = 256 blocks, 512 threads (8 waves).
// A (128 rows x 256 K) in REGISTERS per wave (64 rows each, 2 waves per row-half).
// B streamed through LDS dbuf (2 x 128 cols x 256 K bf16 = 128 KB).
// Waves: wr = wave>>2 (rows wr*64..+64), wc = wave&3 (cols wc*32..+32 of tile).
// MFMA: 32x32x16 bf16, 2 m-frags x 1 n-frag, 16 k-steps.
// PASS 0: per-lane exp accumulation -> one reduction at end -> psum[row][cg*4+wc].
// PASS 1: prob = exp(logit) * invd[row], stores issued after barrier (overlap).
template <int PASS>
__global__ __launch_bounds__(512, 2) void big_gemm(
    const unsigned short* __restrict__ ebf,
    const unsigned short* __restrict__ embbf,
    const float* __restrict__ vbias,
    float* __restrict__ psum,
    const float* __restrict__ denom,
    float* __restrict__ prob) {
    __shared__ unsigned short sB[2][TN * 256];   // 128 KB

    int bid = blockIdx.x;
    int rt = bid >> 3;           // 32 row tiles
    int cg = bid & 7;            // col group == XCD
    int row0 = rt * 128;
    int tid = threadIdx.x;
    int wave = tid >> 6, lane = tid & 63;
    int l31 = lane & 31, hi = lane >> 5;
    int wr = wave >> 2, wc = wave & 3;
    int nmy = (NCT3 - cg + CG - 1) / CG;   // tiles ct = cg, cg+8, ...

    // ---- A into registers: a[mf][ks], row = row0 + wr*64 + mf*32 + l31,
    //      k = ks*16 + hi*8 + i
    bf16x8 a[2][16];
    {
        const unsigned short* ab =
            ebf + (size_t)(row0 + wr * 64 + l31) * 256 + hi * 8;
#pragma unroll
        for (int mf = 0; mf < 2; ++mf)
#pragma unroll
            for (int ks = 0; ks < 16; ++ks)
                a[mf][ks] = *reinterpret_cast<const bf16x8*>(ab + mf * 32 * 256 + ks * 16);
    }

    // ---- stage helper: LDS layout col-major [col][256k], 16B chunk swizzle ^ (col&7)
    auto stage = [&](int ct, int buf) {
        int col0 = ct * TN;
#pragma unroll
        for (int i = 0; i < 8; ++i) {
            int col = i * 16 + wave * 2 + hi;               // per-lane (for src only)
            int gcol = col0 + col; if (gcol >= VOC) gcol = VOC - 1;
            const unsigned short* src =
                embbf + (size_t)gcol * 256 + ((l31 ^ (col & 7)) * 8);
            // wave-uniform LDS base; lanes write base + lane*16
            unsigned short* dst = (unsigned short*)sB[buf] + (size_t)(i * 512 + wave * 64) * 8;
            __builtin_amdgcn_global_load_lds(
                (const __attribute__((address_space(1))) void*)src,
                (__attribute__((address_space(3))) void*)dst, 16, 0, 0);
        }
    };

    stage(cg, 0);
    asm volatile("s_waitcnt vmcnt(0)" ::: "memory");
    __syncthreads();

    float invd[2][16];
    if (PASS == 1) {
#pragma unroll
        for (int mf = 0; mf < 2; ++mf)
#pragma unroll
            for (int r = 0; r < 16; ++r) {
                int row = row0 + wr * 64 + mf * 32 + (r & 3) + 8 * (r >> 2) + 4 * hi;
                invd[mf][r] = 1.f / denom[row];
            }
    }
    float es[2][16];
    if (PASS == 0) {
#pragma unroll
        for (int mf = 0; mf < 2; ++mf)
#pragma unroll
            for (int r = 0; r < 16; ++r) es[mf][r] = 0.f;
    }

    f32x16 zz = {0.f,0.f,0.f,0.f,0.f,0.f,0.f,0.f,0.f,0.f,0.f,0.f,0.f,0.f,0.f,0.f};

    for (int it = 0; it < nmy; ++it) {
        int ct = cg + it * CG;
        if (it + 1 < nmy) stage(ct + CG, (it + 1) & 1);

        int gc = ct * TN + wc * 32 + l31;
        float bvb = (gc < VOC) ? vbias[gc] : -1e4f;

        const unsigned short* sBc = (const unsigned short*)sB[it & 1];
        int bcol = wc * 32 + l31;
        f32x16 c0 = zz, c1 = zz;
#pragma unroll
        for (int ks = 0; ks < 16; ++ks) {
            int kc = ks * 2 + hi;
            bf16x8 b = *reinterpret_cast<const bf16x8*>(
                sBc + bcol * 256 + ((kc ^ (bcol & 7)) * 8));
            c0 = __builtin_amdgcn_mfma_f32_32x32x16_bf16(a[0][ks], b, c0, 0, 0, 0);
            c1 = __builtin_amdgcn_mfma_f32_32x32x16_bf16(a[1][ks], b, c1, 0, 0, 0);
        }

        asm volatile("s_waitcnt vmcnt(0)" ::: "memory");
        __syncthreads();

        // epilogue after barrier: overlaps with next iteration's staging/compute
        if (PASS == 0) {
#pragma unroll
            for (int r = 0; r < 16; ++r) {
                es[0][r] += __expf(c0[r] + bvb);
                es[1][r] += __expf(c1[r] + bvb);
            }
        } else {
            if (gc < VOC) {
#pragma unroll
                for (int r = 0; r < 16; ++r) {
                    int rowr = row0 + wr * 64 + (r & 3) + 8 * (r >> 2) + 4 * hi;
                    prob[(size_t)rowr * VOC + gc] = __expf(c0[r] + bvb) * invd[0][r];
                    prob[(size_t)(rowr + 32) * VOC + gc] = __expf(c1[r] + bvb) * invd[1][r];
                }
            }
        }
    }

    if (PASS == 0) {
        // reduce over the 32 cols (l31) per row; lanes l31==0 write
#pragma unroll
        for (int mf = 0; mf < 2; ++mf)
#pragma unroll
            for (int r = 0; r < 16; ++r) {
                float v = es[mf][r];
#pragma unroll
                for (int off = 1; off < 32; off <<= 1) v += __shfl_xor(v, off);
                if (l31 == 0) {
                    int row = row0 + wr * 64 + mf * 32 + (r & 3) + 8 * (r >> 2) + 4 * hi;
                    psum[(size_t)row * 32 + cg * 4 + wc] = v;
                }
            }
    }
}

// ---------------------------------------------------------------- finalize: denom + loss
__global__ __launch_bounds__(64) void finalize_k(
    const float* __restrict__ psum,
    const unsigned short* __restrict__ ebf, const unsigned short* __restrict__ embbf,
    const float* __restrict__ vbias, const int* __restrict__ labels,
    float* __restrict__ denom, float* __restrict__ loss) {
    int n = blockIdx.x, lane = threadIdx.x;
    float s = (lane < 32) ? psum[(size_t)n * 32 + lane] : 0.f;
#pragma unroll
    for (int off = 1; off < 32; off <<= 1) s += __shfl_xor(s, off);
    int lf = labels[n];
    const unsigned short* ev = ebf + n * 256;
    const unsigned short* mv = embbf + (size_t)lf * 256;
    float p = 0.f;
#pragma unroll
    for (int i = 0; i < 4; ++i) p += bf2f(ev[lane * 4 + i]) * bf2f(mv[lane * 4 + i]);
#pragma unroll
    for (int off = 1; off < 64; off <<= 1) p += __shfl_xor(p, off);
    if (lane == 0) {
        denom[n] = s;
        loss[n] = logf(s) - (p + vbias[lf]);
    }
}

// ---------------------------------------------------------------- launch
extern "C" void kernel_launch(void* const* d_in, const int* in_sizes, int n_in,
                              void* d_out, int out_size, void* d_ws, size_t ws_size,
                              hipStream_t stream) {
    const float* x      = (const float*)d_in[0];
    const int*   labels = (const int*)d_in[1];
    const int*   xb     = (const int*)d_in[2];
    const float* Wsh    = (const float*)d_in[3];
    const float* bsh    = (const float*)d_in[4];
    const float* Wsp    = (const float*)d_in[5];
    const float* bsp    = (const float*)d_in[6];
    const float* wg     = (const float*)d_in[7];
    const float* vbias  = (const float*)d_in[8];
    const float* emb    = (const float*)d_in[9];
    const float* gamma  = (const float*)d_in[10];
    const float* beta   = (const float*)d_in[11];

    char* ws = (char*)d_ws;
    unsigned short* xbf   = (unsigned short*)(ws + 0);          // 2,097,152
    unsigned short* embbf = (unsigned short*)(ws + 2097152);    // 25,731,584
    unsigned short* Wtbf  = (unsigned short*)(ws + 27828736);   // 1,310,720
    float* cexp           = (float*)(ws + 29360128);            // 41,943,040
    unsigned short* ebf   = (unsigned short*)(ws + 71303168);   // 2,097,152
    float* psum           = (float*)(ws + 73400320);            // 524,288
    float* denom          = (float*)(ws + 73924608);            // 16,384

    float* prob = (float*)d_out;
    float* loss = prob + PROB_ELEMS;

    conv_f32_bf16<<<dim3(512), dim3(256), 0, stream>>>(x, xbf, NTOK * HID / 4);
    conv_f32_bf16<<<dim3(2048), dim3(256), 0, stream>>>(emb, embbf, VOC * HID / 4);
    wt_transpose<<<dim3(40, 4), dim3(256), 0, stream>>>(Wsh, Wsp, Wtbf);
    expert_gemm<<<dim3(64 * 20), dim3(256), 0, stream>>>(xbf, Wtbf, bsh, bsp, cexp);
    combine_ln<<<dim3(NTOK), dim3(256), 0, stream>>>(x, xb, wg, cexp, gamma, beta, ebf);
    big_gemm<0><<<dim3(256), dim3(512), 0, stream>>>(ebf, embbf, vbias, psum, nullptr, nullptr);
    finalize_k<<<dim3(NTOK), dim3(64), 0, stream>>>(psum, ebf, embbf, vbias, labels, denom, loss);
    big_gemm<1><<<dim3(256), dim3(512), 0, stream>>>(ebf, embbf, vbias, nullptr, denom, prob);
}